// Round 1
// baseline (259.619 us; speedup 1.0000x reference)
//
#include <hip/hip_runtime.h>
#include <hip/hip_bf16.h>
#include <hip/hip_cooperative_groups.h>

namespace cg = cooperative_groups;

typedef __attribute__((ext_vector_type(4))) float f32x4;
typedef __attribute__((ext_vector_type(8))) __bf16 bf16x8;
typedef __attribute__((ext_vector_type(4))) unsigned int uint4v;

constexpr int M = 16384;
constexpr int N = 1024;
constexpr int K = 2048;
constexpr int BM = 256, BN = 256, BK = 32;  // 3-slot pipelined 256^2 tile
constexpr int NK = K / BK;                  // 64 windows
constexpr float BN_EPS = 1e-5f;
constexpr int TM2 = M / BM;  // 64 row-tiles (psum partials)

// async 16B global -> LDS (lds dest must be wave-uniform; HW adds lane*16)
#define GLOAD_LDS16(g, l)                                                      \
  __builtin_amdgcn_global_load_lds(                                            \
      (const __attribute__((address_space(1))) void*)(g),                      \
      (__attribute__((address_space(3))) void*)(l), 16, 0, 0)

#define SB0 __builtin_amdgcn_sched_barrier(0)

__device__ __forceinline__ unsigned sgnbf(float f) {
  return (f >= 0.f) ? 0x3F80u : 0xBF80u;
}
__global__ __launch_bounds__(256) void binw_kernel(
    const float* __restrict__ w, uint4v* __restrict__ wb) {
  size_t i = (size_t)blockIdx.x * 256 + threadIdx.x;
  const f32x4* win = (const f32x4*)w;
  f32x4 v0 = win[i * 2];
  f32x4 v1 = win[i * 2 + 1];
  uint4v o;
  o.x = sgnbf(v0[0]) | (sgnbf(v0[1]) << 16);
  o.y = sgnbf(v0[2]) | (sgnbf(v0[3]) << 16);
  o.z = sgnbf(v1[0]) | (sgnbf(v1[1]) << 16);
  o.w = sgnbf(v1[2]) | (sgnbf(v1[3]) << 16);
  wb[i] = o;
}

// ---- bf16 GEMM: 256^2 tile, 16 waves (4x4, 64x64 each), 3-slot pipeline ----
// Fully fused with BatchNorm: grid = 256 blocks = 1 block/CU (104 KB LDS),
// cooperative launch. After the K loop the accumulators ARE the Y tile;
// write only psum/psq partials, grid-sync, finalize per-column scale/shift,
// apply to live accumulators, store Y exactly once. Eliminates the 134 MB
// Y round-trip of the separate bnapply kernel.
__global__ __launch_bounds__(1024) void gemm_bin_kernel(
    const float* __restrict__ Af, const unsigned short* __restrict__ B,
    float* __restrict__ Y, float* __restrict__ psum, float* __restrict__ psq,
    const float* __restrict__ gamma, const float* __restrict__ beta) {
  __shared__ unsigned short As[3][BM * BK];  // 48 KiB
  __shared__ unsigned short Bs[3][BN * BK];  // 48 KiB
  __shared__ float redsum[4][BN];            // 4 KiB (reused: scale)
  __shared__ float redsq[4][BN];             // 4 KiB (reused: shift)

  const int tid = threadIdx.x;
  const int wid = tid >> 6;
  const int lane = tid & 63;
  const int wr = wid >> 2, wc = wid & 3;  // 4x4 wave grid, wave owns 64x64

  // T1: XCD swizzle (grid 256, %8==0): XCD owns contiguous tm range.
  const int bid = blockIdx.x;
  const int swz = (bid & 7) * 32 + (bid >> 3);
  const int tm = swz >> 2, tn = swz & 3;
  const size_t m0 = (size_t)tm * BM, n0 = (size_t)tn * BN;

  const int frow = lane & 15;  // fragment row/col within 16x16
  const int fcb = lane >> 4;   // k chunk 0..3
  // T2 swizzle: 16B-chunk ^= (row>>1)&3 (involution; R5-verified: 0 conflicts)
  const int swzc = fcb ^ ((frow >> 1) & 3);
  const int aoff = (wr * 64 + frow) * BK + swzc * 8;  // + m*512
  const int boff = (wc * 64 + frow) * BK + swzc * 8;  // + n*512

  f32x4 acc[4][4];
#pragma unroll
  for (int m = 0; m < 4; ++m)
#pragma unroll
    for (int n = 0; n < 4; ++n)
#pragma unroll
      for (int j = 0; j < 4; ++j) acc[m][n][j] = 0.f;

  // B staging (gload_lds): unit id = tid (1024 x 16B = 16KB tile); row=id>>2,
  // lds chunk c = id&3, global chunk = c ^ ((row>>1)&3). 1 GLOAD per wave.
  const int r0s = tid >> 2;
  const int c0s = (tid & 3) ^ ((r0s >> 1) & 3);
  const unsigned short* pB = B + (n0 + r0s) * (size_t)K + c0s * 8;

  // A staging (reg): thread t covers row rA0 = t>>2, 8 consecutive floats at
  // global chunk cA = (t&3)^((rA0>>1)&3); 2x dwordx4 load, cvt, 1 ds_write_b128
  // at lds chunk t&3 (swizzle involution matches fragment reads).
  const int rA0 = tid >> 2;
  const int cA = (tid & 3) ^ ((rA0 >> 1) & 3);
  const float* pAf = Af + (m0 + rA0) * (size_t)K + cA * 8;
  const int awb0 = rA0 * 32 + (tid & 3) * 8;  // ushort index
  f32x4 As_[2];

#define A_ISSUE(ktv)                                                           \
  {                                                                            \
    const size_t k0_ = (size_t)(ktv)*BK;                                       \
    As_[0] = *(const f32x4*)(pAf + k0_);                                       \
    As_[1] = *(const f32x4*)(pAf + k0_ + 4);                                   \
  }
#define B_ISSUE(ss, ktv)                                                       \
  { GLOAD_LDS16(pB + (size_t)(ktv)*BK, &Bs[ss][wid * 512]); }
#define A_WRITE(ss)                                                            \
  {                                                                            \
    bf16x8 v0_;                                                                \
    _Pragma("unroll") for (int j_ = 0; j_ < 4; ++j_) {                         \
      v0_[j_] = (__bf16)As_[0][j_];                                            \
      v0_[4 + j_] = (__bf16)As_[1][j_];                                        \
    }                                                                          \
    *(bf16x8*)&As[ss][awb0] = v0_;                                             \
  }

#define WAITL                                                                  \
  asm volatile("s_waitcnt lgkmcnt(0)" ::: "memory");                           \
  __builtin_amdgcn_sched_barrier(0);

#define LDA(s, m) (*(const bf16x8*)&As[s][aoff + (m)*512])
#define LDB(s, n) (*(const bf16x8*)&Bs[s][boff + (n)*512])

#define MF(mi, av)                                                             \
  _Pragma("unroll") for (int n = 0; n < 4; ++n) acc[mi][n] =                   \
      __builtin_amdgcn_mfma_f32_16x16x32_bf16(av, b_[n], acc[mi][n], 0, 0, 0);

// MODE: 0 = steady (stage tile ktv+2), 1 = pre-last (vmcnt(0)), 2 = last
#define WINDOW(s, ktv, MODE)                                                   \
  {                                                                            \
    bf16x8 b_[4], a0, a1, a2, a3;                                              \
    if (MODE == 0) {                                                           \
      A_ISSUE((ktv) + 2); /* oldest in VMEM queue; max latency cover */        \
      SB0;                                                                     \
    }                                                                          \
    b_[0] = LDB(s, 0);                                                         \
    b_[1] = LDB(s, 1);                                                         \
    b_[2] = LDB(s, 2);                                                         \
    b_[3] = LDB(s, 3);                                                         \
    a0 = LDA(s, 0);                                                            \
    a1 = LDA(s, 1);                                                            \
    if (MODE == 0) {                                                           \
      B_ISSUE(((ktv) + 2) % 3, (ktv) + 2); /* newest in VMEM queue */          \
      SB0;                                                                     \
    }                                                                          \
    WAITL                                                                      \
    __builtin_amdgcn_s_setprio(1);                                             \
    a2 = LDA(s, 2);                                                            \
    a3 = LDA(s, 3);                                                            \
    MF(0, a0)                                                                  \
    MF(1, a1)                                                                  \
    __builtin_amdgcn_s_setprio(0);                                             \
    WAITL                                                                      \
    __builtin_amdgcn_s_setprio(1);                                             \
    MF(2, a2)                                                                  \
    MF(3, a3)                                                                  \
    __builtin_amdgcn_s_setprio(0);                                             \
    SB0;                                                                       \
    if (MODE == 0) {                                                           \
      asm volatile("s_waitcnt vmcnt(1)" ::: "memory");                         \
      A_WRITE(((ktv) + 2) % 3);                                                \
    } else if (MODE == 1) {                                                    \
      asm volatile("s_waitcnt vmcnt(0)" ::: "memory");                         \
    }                                                                          \
    if (MODE != 2) {                                                           \
      asm volatile("s_waitcnt lgkmcnt(0)" ::: "memory");                       \
      __builtin_amdgcn_s_barrier();                                            \
      asm volatile("" ::: "memory");                                           \
    }                                                                          \
  }

  // prologue: stage tiles 0,1 into slots 0,1 (A via reg+cvt, B via gload).
  // Order pinned: A oldest, B newest -> each vmcnt(1) keeps newest B.
  A_ISSUE(0);
  SB0;
  B_ISSUE(0, 0);
  SB0;
  asm volatile("s_waitcnt vmcnt(1)" ::: "memory");  // drains A(0) pair
  A_WRITE(0);
  A_ISSUE(1);
  SB0;
  B_ISSUE(1, 1);
  SB0;
  asm volatile("s_waitcnt vmcnt(1)" ::: "memory");  // drains B(0), A(1)
  A_WRITE(1);
  asm volatile("s_waitcnt lgkmcnt(0)" ::: "memory");
  __builtin_amdgcn_s_barrier();
  asm volatile("" ::: "memory");

  for (int kt = 0; kt < NK - 4; kt += 3) {  // kt = 0..57 -> windows 0..59
    WINDOW(0, kt, 0);
    WINDOW(1, kt + 1, 0);
    WINDOW(2, kt + 2, 0);
  }
  WINDOW(0, NK - 4, 0);  // kt=60 stages tile 62
  WINDOW(1, NK - 3, 0);  // kt=61 stages tile 63
  WINDOW(2, NK - 2, 1);  // kt=62: no stage, vmcnt(0)
  WINDOW(0, NK - 1, 2);  // kt=63: no stage, no barrier

  // epilogue 1: fused column partial stats (exact fp32 from accumulators).
  // Y is NOT stored yet — accumulators stay live across the grid barrier.
  float cs[4], cq[4];
#pragma unroll
  for (int n = 0; n < 4; ++n) {
    float s = 0.f, q = 0.f;
#pragma unroll
    for (int m = 0; m < 4; ++m)
#pragma unroll
      for (int j = 0; j < 4; ++j) {
        float v = acc[m][n][j];
        s += v;
        q += v * v;
      }
    cs[n] = s;
    cq[n] = q;
  }
#pragma unroll
  for (int n = 0; n < 4; ++n) {  // reduce over fcb (lane bits 4-5)
    cs[n] += __shfl_xor(cs[n], 16);
    cs[n] += __shfl_xor(cs[n], 32);
    cq[n] += __shfl_xor(cq[n], 16);
    cq[n] += __shfl_xor(cq[n], 32);
  }
  __syncthreads();
  if (fcb == 0) {
#pragma unroll
    for (int n = 0; n < 4; ++n) {
      redsum[wr][wc * 64 + n * 16 + frow] = cs[n];
      redsq[wr][wc * 64 + n * 16 + frow] = cq[n];
    }
  }
  __syncthreads();
  if (tid < BN) {
    const size_t c = n0 + tid;
    psum[(size_t)tm * N + c] =
        redsum[0][tid] + redsum[1][tid] + redsum[2][tid] + redsum[3][tid];
    psq[(size_t)tm * N + c] =
        redsq[0][tid] + redsq[1][tid] + redsq[2][tid] + redsq[3][tid];
  }

  // device-scope release: flush dirty psum/psq L2 lines so cross-XCD reads
  // after the grid barrier see them (G16). Only ~512 KB dirty -> cheap.
  __threadfence();
  cg::this_grid().sync();
  __threadfence();  // acquire side (invalidate), insurance

  // epilogue 2: finalize column stats for this block's 256 columns.
  // All 1024 threads: thread (qd,cl) sums 16 of the 64 row-tile partials.
  const int cl = tid & 255;
  const int qd = tid >> 8;
  {
    float s = 0.f, q = 0.f;
    const float* ps = psum + n0 + cl;
    const float* pq = psq + n0 + cl;
    for (int i = qd * 16; i < qd * 16 + 16; ++i) {
      s += ps[(size_t)i * N];
      q += pq[(size_t)i * N];
    }
    redsum[qd][cl] = s;
    redsq[qd][cl] = q;
  }
  __syncthreads();
  if (tid < 256) {
    const float S =
        redsum[0][cl] + redsum[1][cl] + redsum[2][cl] + redsum[3][cl];
    const float Q = redsq[0][cl] + redsq[1][cl] + redsq[2][cl] + redsq[3][cl];
    const float mean = S * (1.f / (float)M);
    const float var = Q * (1.f / (float)M) - mean * mean;
    const float inv = rsqrtf(var + BN_EPS);
    const float sc = gamma[n0 + cl] * inv;
    redsum[0][cl] = sc;                      // scale
    redsq[0][cl] = beta[n0 + cl] - mean * sc;  // shift
  }
  __syncthreads();

  // epilogue 3: apply BN to live accumulators, store Y exactly once.
  // C/D layout: col = lane&15, row = (lane>>4)*4 + j
#pragma unroll
  for (int m = 0; m < 4; ++m) {
    const size_t r0 = m0 + wr * 64 + m * 16 + fcb * 4;
#pragma unroll
    for (int n = 0; n < 4; ++n) {
      const int cloc = wc * 64 + n * 16 + frow;
      const float sc = redsum[0][cloc];
      const float sh = redsq[0][cloc];
      float* yp = Y + r0 * N + n0 + cloc;
#pragma unroll
      for (int j = 0; j < 4; ++j) yp[(size_t)j * N] = acc[m][n][j] * sc + sh;
    }
  }
}

extern "C" void kernel_launch(void* const* d_in, const int* in_sizes, int n_in,
                              void* d_out, int out_size, void* d_ws,
                              size_t ws_size, hipStream_t stream) {
  const float* x = (const float*)d_in[0];
  const float* w = (const float*)d_in[1];
  // d_in[2] = bias: a per-column constant shift cancels exactly in BatchNorm
  const float* gamma = (const float*)d_in[3];
  const float* beta = (const float*)d_in[4];
  float* Y = (float*)d_out;  // written once, already normalized

  char* ws = (char*)d_ws;
  uint4v* wb = (uint4v*)ws;  // 4 MiB
  float* psum = (float*)(ws + (size_t)N * K * 2);
  float* psq = psum + (size_t)TM2 * N;  // 256 KiB each

  binw_kernel<<<(N * K / 8) / 256, 256, 0, stream>>>(w, wb);

  const unsigned short* Bp = (const unsigned short*)wb;
  void* args[] = {(void*)&x,    (void*)&Bp,    (void*)&Y,   (void*)&psum,
                  (void*)&psq,  (void*)&gamma, (void*)&beta};
  // grid 256 = 1 block/CU (104 KB LDS, 1024 thr) -> co-residency guaranteed
  hipLaunchCooperativeKernel(reinterpret_cast<void*>(gemm_bin_kernel),
                             dim3((M / BM) * (N / BN)), dim3(1024), args, 0,
                             stream);
}

// Round 2
// 119.500 us; speedup vs baseline: 2.1725x; 2.1725x over previous
//
#include <hip/hip_runtime.h>
#include <hip/hip_bf16.h>

typedef __attribute__((ext_vector_type(4))) float f32x4;
typedef __attribute__((ext_vector_type(8))) __bf16 bf16x8;
typedef __attribute__((ext_vector_type(4))) unsigned int uint4v;

constexpr int M = 16384;
constexpr int N = 1024;
constexpr int K = 2048;
constexpr int BM = 256, BN = 256, BK = 32;  // 3-slot pipelined 256^2 tile
constexpr int NK = K / BK;                  // 64 windows
constexpr float BN_EPS = 1e-5f;
constexpr int TM2 = M / BM;  // 64 row-tiles (psum partials)
constexpr int GRID = (M / BM) * (N / BN);  // 256 blocks = 1/CU

// async 16B global -> LDS (lds dest must be wave-uniform; HW adds lane*16)
#define GLOAD_LDS16(g, l)                                                      \
  __builtin_amdgcn_global_load_lds(                                            \
      (const __attribute__((address_space(1))) void*)(g),                      \
      (__attribute__((address_space(3))) void*)(l), 16, 0, 0)

#define SB0 __builtin_amdgcn_sched_barrier(0)

__device__ __forceinline__ unsigned sgnbf(float f) {
  return (f >= 0.f) ? 0x3F80u : 0xBF80u;
}
__global__ __launch_bounds__(256) void binw_kernel(
    const float* __restrict__ w, uint4v* __restrict__ wb,
    unsigned* __restrict__ ctr) {
  if (blockIdx.x == 0 && threadIdx.x == 0) *ctr = 0;  // barrier reset
  size_t i = (size_t)blockIdx.x * 256 + threadIdx.x;
  const f32x4* win = (const f32x4*)w;
  f32x4 v0 = win[i * 2];
  f32x4 v1 = win[i * 2 + 1];
  uint4v o;
  o.x = sgnbf(v0[0]) | (sgnbf(v0[1]) << 16);
  o.y = sgnbf(v0[2]) | (sgnbf(v0[3]) << 16);
  o.z = sgnbf(v1[0]) | (sgnbf(v1[1]) << 16);
  o.w = sgnbf(v1[2]) | (sgnbf(v1[3]) << 16);
  wb[i] = o;
}

// ---- bf16 GEMM: 256^2 tile, 16 waves (4x4, 64x64 each), 3-slot pipeline ----
// Fully fused with BatchNorm: grid = 256 blocks = 1 block/CU (104 KB LDS),
// cooperative launch (residency guarantee only). After the K loop the
// accumulators ARE the Y tile; write only psum/psq partials, cross the grid
// barrier (hand-rolled: thread0-only fence+ticket+spin — cg::sync cost
// ~150us of idle because every thread did system-scope fencing), finalize
// per-column scale/shift, apply to live accumulators, store Y exactly once.
__global__ __launch_bounds__(1024) void gemm_bin_kernel(
    const float* __restrict__ Af, const unsigned short* __restrict__ B,
    float* __restrict__ Y, float* __restrict__ psum, float* __restrict__ psq,
    const float* __restrict__ gamma, const float* __restrict__ beta,
    unsigned* __restrict__ ctr) {
  __shared__ unsigned short As[3][BM * BK];  // 48 KiB
  __shared__ unsigned short Bs[3][BN * BK];  // 48 KiB
  __shared__ float redsum[4][BN];            // 4 KiB (reused: scale)
  __shared__ float redsq[4][BN];             // 4 KiB (reused: shift)

  const int tid = threadIdx.x;
  const int wid = tid >> 6;
  const int lane = tid & 63;
  const int wr = wid >> 2, wc = wid & 3;  // 4x4 wave grid, wave owns 64x64

  // T1: XCD swizzle (grid 256, %8==0): XCD owns contiguous tm range.
  const int bid = blockIdx.x;
  const int swz = (bid & 7) * 32 + (bid >> 3);
  const int tm = swz >> 2, tn = swz & 3;
  const size_t m0 = (size_t)tm * BM, n0 = (size_t)tn * BN;

  const int frow = lane & 15;  // fragment row/col within 16x16
  const int fcb = lane >> 4;   // k chunk 0..3
  // T2 swizzle: 16B-chunk ^= (row>>1)&3 (involution; R5-verified: 0 conflicts)
  const int swzc = fcb ^ ((frow >> 1) & 3);
  const int aoff = (wr * 64 + frow) * BK + swzc * 8;  // + m*512
  const int boff = (wc * 64 + frow) * BK + swzc * 8;  // + n*512

  f32x4 acc[4][4];
#pragma unroll
  for (int m = 0; m < 4; ++m)
#pragma unroll
    for (int n = 0; n < 4; ++n)
#pragma unroll
      for (int j = 0; j < 4; ++j) acc[m][n][j] = 0.f;

  // B staging (gload_lds): unit id = tid (1024 x 16B = 16KB tile); row=id>>2,
  // lds chunk c = id&3, global chunk = c ^ ((row>>1)&3). 1 GLOAD per wave.
  const int r0s = tid >> 2;
  const int c0s = (tid & 3) ^ ((r0s >> 1) & 3);
  const unsigned short* pB = B + (n0 + r0s) * (size_t)K + c0s * 8;

  // A staging (reg): thread t covers row rA0 = t>>2, 8 consecutive floats at
  // global chunk cA = (t&3)^((rA0>>1)&3); 2x dwordx4 load, cvt, 1 ds_write_b128
  // at lds chunk t&3 (swizzle involution matches fragment reads).
  const int rA0 = tid >> 2;
  const int cA = (tid & 3) ^ ((rA0 >> 1) & 3);
  const float* pAf = Af + (m0 + rA0) * (size_t)K + cA * 8;
  const int awb0 = rA0 * 32 + (tid & 3) * 8;  // ushort index
  f32x4 As_[2];

#define A_ISSUE(ktv)                                                           \
  {                                                                            \
    const size_t k0_ = (size_t)(ktv)*BK;                                       \
    As_[0] = *(const f32x4*)(pAf + k0_);                                       \
    As_[1] = *(const f32x4*)(pAf + k0_ + 4);                                   \
  }
#define B_ISSUE(ss, ktv)                                                       \
  { GLOAD_LDS16(pB + (size_t)(ktv)*BK, &Bs[ss][wid * 512]); }
#define A_WRITE(ss)                                                            \
  {                                                                            \
    bf16x8 v0_;                                                                \
    _Pragma("unroll") for (int j_ = 0; j_ < 4; ++j_) {                         \
      v0_[j_] = (__bf16)As_[0][j_];                                            \
      v0_[4 + j_] = (__bf16)As_[1][j_];                                        \
    }                                                                          \
    *(bf16x8*)&As[ss][awb0] = v0_;                                             \
  }

#define WAITL                                                                  \
  asm volatile("s_waitcnt lgkmcnt(0)" ::: "memory");                           \
  __builtin_amdgcn_sched_barrier(0);

#define LDA(s, m) (*(const bf16x8*)&As[s][aoff + (m)*512])
#define LDB(s, n) (*(const bf16x8*)&Bs[s][boff + (n)*512])

#define MF(mi, av)                                                             \
  _Pragma("unroll") for (int n = 0; n < 4; ++n) acc[mi][n] =                   \
      __builtin_amdgcn_mfma_f32_16x16x32_bf16(av, b_[n], acc[mi][n], 0, 0, 0);

// MODE: 0 = steady (stage tile ktv+2), 1 = pre-last (vmcnt(0)), 2 = last
#define WINDOW(s, ktv, MODE)                                                   \
  {                                                                            \
    bf16x8 b_[4], a0, a1, a2, a3;                                              \
    if (MODE == 0) {                                                           \
      A_ISSUE((ktv) + 2); /* oldest in VMEM queue; max latency cover */        \
      SB0;                                                                     \
    }                                                                          \
    b_[0] = LDB(s, 0);                                                         \
    b_[1] = LDB(s, 1);                                                         \
    b_[2] = LDB(s, 2);                                                         \
    b_[3] = LDB(s, 3);                                                         \
    a0 = LDA(s, 0);                                                            \
    a1 = LDA(s, 1);                                                            \
    if (MODE == 0) {                                                           \
      B_ISSUE(((ktv) + 2) % 3, (ktv) + 2); /* newest in VMEM queue */          \
      SB0;                                                                     \
    }                                                                          \
    WAITL                                                                      \
    __builtin_amdgcn_s_setprio(1);                                             \
    a2 = LDA(s, 2);                                                            \
    a3 = LDA(s, 3);                                                            \
    MF(0, a0)                                                                  \
    MF(1, a1)                                                                  \
    __builtin_amdgcn_s_setprio(0);                                             \
    WAITL                                                                      \
    __builtin_amdgcn_s_setprio(1);                                             \
    MF(2, a2)                                                                  \
    MF(3, a3)                                                                  \
    __builtin_amdgcn_s_setprio(0);                                             \
    SB0;                                                                       \
    if (MODE == 0) {                                                           \
      asm volatile("s_waitcnt vmcnt(1)" ::: "memory");                         \
      A_WRITE(((ktv) + 2) % 3);                                                \
    } else if (MODE == 1) {                                                    \
      asm volatile("s_waitcnt vmcnt(0)" ::: "memory");                         \
    }                                                                          \
    if (MODE != 2) {                                                           \
      asm volatile("s_waitcnt lgkmcnt(0)" ::: "memory");                       \
      __builtin_amdgcn_s_barrier();                                            \
      asm volatile("" ::: "memory");                                           \
    }                                                                          \
  }

  // prologue: stage tiles 0,1 into slots 0,1 (A via reg+cvt, B via gload).
  // Order pinned: A oldest, B newest -> each vmcnt(1) keeps newest B.
  A_ISSUE(0);
  SB0;
  B_ISSUE(0, 0);
  SB0;
  asm volatile("s_waitcnt vmcnt(1)" ::: "memory");  // drains A(0) pair
  A_WRITE(0);
  A_ISSUE(1);
  SB0;
  B_ISSUE(1, 1);
  SB0;
  asm volatile("s_waitcnt vmcnt(1)" ::: "memory");  // drains B(0), A(1)
  A_WRITE(1);
  asm volatile("s_waitcnt lgkmcnt(0)" ::: "memory");
  __builtin_amdgcn_s_barrier();
  asm volatile("" ::: "memory");

  for (int kt = 0; kt < NK - 4; kt += 3) {  // kt = 0..57 -> windows 0..59
    WINDOW(0, kt, 0);
    WINDOW(1, kt + 1, 0);
    WINDOW(2, kt + 2, 0);
  }
  WINDOW(0, NK - 4, 0);  // kt=60 stages tile 62
  WINDOW(1, NK - 3, 0);  // kt=61 stages tile 63
  WINDOW(2, NK - 2, 1);  // kt=62: no stage, vmcnt(0)
  WINDOW(0, NK - 1, 2);  // kt=63: no stage, no barrier

  // epilogue 1: fused column partial stats (exact fp32 from accumulators).
  // Y is NOT stored yet — accumulators stay live across the grid barrier.
  float cs[4], cq[4];
#pragma unroll
  for (int n = 0; n < 4; ++n) {
    float s = 0.f, q = 0.f;
#pragma unroll
    for (int m = 0; m < 4; ++m)
#pragma unroll
      for (int j = 0; j < 4; ++j) {
        float v = acc[m][n][j];
        s += v;
        q += v * v;
      }
    cs[n] = s;
    cq[n] = q;
  }
#pragma unroll
  for (int n = 0; n < 4; ++n) {  // reduce over fcb (lane bits 4-5)
    cs[n] += __shfl_xor(cs[n], 16);
    cs[n] += __shfl_xor(cs[n], 32);
    cq[n] += __shfl_xor(cq[n], 16);
    cq[n] += __shfl_xor(cq[n], 32);
  }
  __syncthreads();
  if (fcb == 0) {
#pragma unroll
    for (int n = 0; n < 4; ++n) {
      redsum[wr][wc * 64 + n * 16 + frow] = cs[n];
      redsq[wr][wc * 64 + n * 16 + frow] = cq[n];
    }
  }
  __syncthreads();
  if (tid < BN) {
    const size_t c = n0 + tid;
    psum[(size_t)tm * N + c] =
        redsum[0][tid] + redsum[1][tid] + redsum[2][tid] + redsum[3][tid];
    psq[(size_t)tm * N + c] =
        redsq[0][tid] + redsq[1][tid] + redsq[2][tid] + redsq[3][tid];
  }

  // ---- hand-rolled one-shot grid barrier ----
  // syncthreads: every wave drains vmcnt(0) -> psum/psq stores are in L2.
  // thread0 only: release fence (buffer_wbl2 flushes this XCD's dirty
  // psum/psq lines), device-scope ticket, relaxed spin + sleep backoff,
  // acquire fence (invalidate stale lines). 256 fences total vs cg::sync's
  // per-thread system-scope fencing (~150us idle in R1).
  __syncthreads();
  if (tid == 0) {
    __threadfence();  // release
    const unsigned ticket = __hip_atomic_fetch_add(
        ctr, 1u, __ATOMIC_RELAXED, __HIP_MEMORY_SCOPE_AGENT);
    const unsigned goal = (ticket & ~255u) + 256u;  // same for all 256 blocks
    while ((int)(__hip_atomic_load(ctr, __ATOMIC_RELAXED,
                                   __HIP_MEMORY_SCOPE_AGENT) -
                 goal) < 0) {
      __builtin_amdgcn_s_sleep(16);
    }
    __threadfence();  // acquire
  }
  __syncthreads();

  // epilogue 2: finalize column stats for this block's 256 columns.
  // All 1024 threads: thread (qd,cl) sums 16 of the 64 row-tile partials.
  const int cl = tid & 255;
  const int qd = tid >> 8;
  {
    float s = 0.f, q = 0.f;
    const float* ps = psum + n0 + cl;
    const float* pq = psq + n0 + cl;
    for (int i = qd * 16; i < qd * 16 + 16; ++i) {
      s += ps[(size_t)i * N];
      q += pq[(size_t)i * N];
    }
    redsum[qd][cl] = s;
    redsq[qd][cl] = q;
  }
  __syncthreads();
  if (tid < 256) {
    const float S =
        redsum[0][cl] + redsum[1][cl] + redsum[2][cl] + redsum[3][cl];
    const float Q = redsq[0][cl] + redsq[1][cl] + redsq[2][cl] + redsq[3][cl];
    const float mean = S * (1.f / (float)M);
    const float var = Q * (1.f / (float)M) - mean * mean;
    const float inv = rsqrtf(var + BN_EPS);
    const float sc = gamma[n0 + cl] * inv;
    redsum[0][cl] = sc;                        // scale
    redsq[0][cl] = beta[n0 + cl] - mean * sc;  // shift
  }
  __syncthreads();

  // epilogue 3: apply BN to live accumulators, store Y exactly once.
  // C/D layout: col = lane&15, row = (lane>>4)*4 + j
#pragma unroll
  for (int m = 0; m < 4; ++m) {
    const size_t r0 = m0 + wr * 64 + m * 16 + fcb * 4;
#pragma unroll
    for (int n = 0; n < 4; ++n) {
      const int cloc = wc * 64 + n * 16 + frow;
      const float sc = redsum[0][cloc];
      const float sh = redsq[0][cloc];
      float* yp = Y + r0 * N + n0 + cloc;
#pragma unroll
      for (int j = 0; j < 4; ++j) yp[(size_t)j * N] = acc[m][n][j] * sc + sh;
    }
  }
}

extern "C" void kernel_launch(void* const* d_in, const int* in_sizes, int n_in,
                              void* d_out, int out_size, void* d_ws,
                              size_t ws_size, hipStream_t stream) {
  const float* x = (const float*)d_in[0];
  const float* w = (const float*)d_in[1];
  // d_in[2] = bias: a per-column constant shift cancels exactly in BatchNorm
  const float* gamma = (const float*)d_in[3];
  const float* beta = (const float*)d_in[4];
  float* Y = (float*)d_out;  // written once, already normalized

  char* ws = (char*)d_ws;
  uint4v* wb = (uint4v*)ws;  // 4 MiB
  float* psum = (float*)(ws + (size_t)N * K * 2);
  float* psq = psum + (size_t)TM2 * N;  // 256 KiB each
  unsigned* ctr = (unsigned*)(psq + (size_t)TM2 * N);

  binw_kernel<<<(N * K / 8) / 256, 256, 0, stream>>>(w, wb, ctr);

  const unsigned short* Bp = (const unsigned short*)wb;
  void* args[] = {(void*)&x,   (void*)&Bp,    (void*)&Y,    (void*)&psum,
                  (void*)&psq, (void*)&gamma, (void*)&beta, (void*)&ctr};
  // grid 256 = 1 block/CU (104 KB LDS, 1024 thr) -> co-residency guaranteed
  hipLaunchCooperativeKernel(reinterpret_cast<void*>(gemm_bin_kernel),
                             dim3(GRID), dim3(1024), args, 0, stream);
}